// Round 5
// baseline (4129.501 us; speedup 1.0000x reference)
//
#include <hip/hip_runtime.h>
#include <hip/hip_bf16.h>

// Encoder: e = embed[x]; q = LSTM_q(e); k = LSTM_k(e); A = q @ k^T (per batch)
// B=32, T=512, D=512, NUM_TOKENS=14.
//
// R5 = R3/R4 resubmitted verbatim (both hit infra failures, never ran).
// Persistent-kernel recurrence. 128 WGs (64 per LSTM, 8 h-dims each) loop
// t=0..511 in one dispatch. W_hh slice + pre-table slice + tokens staged in LDS
// once; c-state in registers; only h crosses WGs (global, double-buffered).
// Per-step sync = per-LSTM flag-array barrier (agent-scope release/acquire).

#define TB 32
#define TT 512
#define TD 512
#define NTOK 14

typedef __attribute__((ext_vector_type(8))) short short8;
typedef __attribute__((ext_vector_type(4))) float f32x4;

__device__ __forceinline__ float fsigmoid(float v) { return 1.f / (1.f + __expf(-v)); }
__device__ __forceinline__ float ftanh(float v) {
    float a = fabsf(v);
    float e = __expf(-2.f * a);
    float r = (1.f - e) / (1.f + e);
    return copysignf(r, v);
}
__device__ __forceinline__ unsigned short f2bf(float f) {
    __hip_bfloat16 h = __float2bfloat16(f);
    return __builtin_bit_cast(unsigned short, h);
}

// ---- pre_tab[l][tok][2048] = embed[tok] @ W_ih_l^T + b_ih_l + b_hh_l ----
__global__ __launch_bounds__(256) void pre_tab_kernel(
    const float* __restrict__ embed,
    const float* __restrict__ Wih_q, const float* __restrict__ bih_q, const float* __restrict__ bhh_q,
    const float* __restrict__ Wih_k, const float* __restrict__ bih_k, const float* __restrict__ bhh_k,
    float* __restrict__ pre)
{
    int idx = blockIdx.x * 256 + threadIdx.x;   // 2*14*2048 = 57344 exactly
    int l = idx / (NTOK * 4 * TD);
    int r = idx % (NTOK * 4 * TD);
    int tok = r / (4 * TD), j = r % (4 * TD);
    const float* Wih = l ? Wih_k : Wih_q;
    float acc = l ? (bih_k[j] + bhh_k[j]) : (bih_q[j] + bhh_q[j]);
    const float4* e4 = (const float4*)(embed + (size_t)tok * TD);
    const float4* w4 = (const float4*)(Wih + (size_t)j * TD);
    for (int t2 = 0; t2 < TD / 4; ++t2) {
        float4 e = e4[t2], w = w4[t2];
        acc += e.x * w.x + e.y * w.y + e.z * w.z + e.w * w.w;
    }
    pre[idx] = acc;
}

__global__ void init_flags(int* flags) { flags[threadIdx.x] = 0; }

// ---- persistent LSTM: grid 128, wg>>6 = lstm l, (wg&63)*8 = dim chunk d0 ----
__global__ __launch_bounds__(256) void lstm_persist(
    const float* __restrict__ Whh_q, const float* __restrict__ Whh_k,
    const float* __restrict__ pre,
    const int* __restrict__ x,
    float* __restrict__ qout, float* __restrict__ kout,
    unsigned short* __restrict__ hbf,
    int* __restrict__ flags)
{
    __shared__ unsigned short w_lds[32][512];   // 32 KB, 16B-chunk XOR swizzled
    __shared__ unsigned char  x_lds[TB * TT];   // 16 KB
    __shared__ float          pre_lds[NTOK][32];// [tok][gate*8+dd]
    __shared__ float          g_lds[32][33];

    int wg  = blockIdx.x;
    int l   = wg >> 6;
    int wid = wg & 63;
    int d0  = wid << 3;
    int tid = threadIdx.x;
    int lane = tid & 63;
    int wv = tid >> 6;     // 4 waves
    int mt = wv & 1;       // batch tile
    int nt = wv >> 1;      // gate-row tile

    const float* Whh = l ? Whh_k : Whh_q;

    // stage W slice: LDS row r (=gate*8+dd) <- global row (r>>3)*TD + d0 + (r&7)
    // chunk = 8 bf16 (16 B); swizzle: store chunk c at position c ^ (r&7)
    {
        int r = tid >> 3;
        const float* src = Whh + (size_t)((r >> 3) * TD + d0 + (r & 7)) * TD;
        for (int i = 0; i < 8; ++i) {
            int c = (tid & 7) + 8 * i;
            float4 a = ((const float4*)src)[c * 2];
            float4 b = ((const float4*)src)[c * 2 + 1];
            unsigned short* dst = &w_lds[r][(c ^ (r & 7)) * 8];
            dst[0] = f2bf(a.x); dst[1] = f2bf(a.y); dst[2] = f2bf(a.z); dst[3] = f2bf(a.w);
            dst[4] = f2bf(b.x); dst[5] = f2bf(b.y); dst[6] = f2bf(b.z); dst[7] = f2bf(b.w);
        }
    }
    for (int i = tid; i < TB * TT; i += 256) x_lds[i] = (unsigned char)x[i];
    for (int i = tid; i < NTOK * 32; i += 256) {
        int tok = i >> 5, rr = i & 31;
        pre_lds[tok][rr] = pre[((size_t)l * NTOK + tok) * (4 * TD) + (rr >> 3) * TD + d0 + (rr & 7)];
    }
    __syncthreads();

    int b  = tid >> 3, dd = tid & 7;          // tail mapping
    float creg = 0.f;
    float* hist = l ? kout : qout;
    int* gflags = flags + l * 64;

    for (int t = 0; t < TT; ++t) {
        f32x4 acc = {0.f, 0.f, 0.f, 0.f};
        if (t > 0) {
            // A-frag: h[b][k]; lane: b = mt*16+(lane&15), k-offset (lane>>4)*8
            const unsigned short* hrow = hbf
                + (size_t)((((t - 1) & 1) * 2 + l) * TB + (mt * 16 + (lane & 15))) * TD
                + ((lane >> 4) * 8);
            int rr = nt * 16 + (lane & 15);   // LDS W row
#pragma unroll
            for (int kk = 0; kk < 16; ++kk) {
                short8 a = *(const short8*)(hrow + kk * 32);
                int c = kk * 4 + (lane >> 4);
                short8 bfr = *(const short8*)&w_lds[rr][(c ^ (rr & 7)) * 8];
                acc = __builtin_amdgcn_mfma_f32_16x16x32_bf16(a, bfr, acc, 0, 0, 0);
            }
        }
        // C/D: col(lane&15)->gate-row, row((lane>>4)*4+reg)->batch
        {
            int gr = nt * 16 + (lane & 15);
            int gb = mt * 16 + ((lane >> 4) << 2);
#pragma unroll
            for (int r2 = 0; r2 < 4; ++r2) g_lds[gr][gb + r2] = acc[r2];
        }
        __syncthreads();

        // pointwise tail: thread <-> (b, dd)
        {
            int tok = x_lds[b * TT + t];
            float gi = g_lds[dd][b]      + pre_lds[tok][dd];
            float gf = g_lds[8 + dd][b]  + pre_lds[tok][8 + dd];
            float gg = g_lds[16 + dd][b] + pre_lds[tok][16 + dd];
            float go = g_lds[24 + dd][b] + pre_lds[tok][24 + dd];
            float i_ = fsigmoid(gi), f_ = fsigmoid(gf), g_ = ftanh(gg), o_ = fsigmoid(go);
            creg = f_ * creg + i_ * g_;
            float h = o_ * ftanh(creg);
            hist[((size_t)b * TT + t) * TD + d0 + dd] = h;
            hbf[(size_t)(((t & 1) * 2 + l) * TB + b) * TD + d0 + dd] = f2bf(h);
        }
        __syncthreads();   // all waves' h-stores issued

        if (t != TT - 1) {
            if (tid == 0) {
                __builtin_amdgcn_fence(__ATOMIC_RELEASE, "agent");
                __hip_atomic_store(&gflags[wid], t + 1, __ATOMIC_RELAXED, __HIP_MEMORY_SCOPE_AGENT);
            }
            if (tid < 64) {
                for (;;) {
                    int v = __hip_atomic_load(&gflags[tid], __ATOMIC_RELAXED, __HIP_MEMORY_SCOPE_AGENT);
                    if (__all(v >= t + 1)) break;
                    __builtin_amdgcn_s_sleep(4);
                }
                __builtin_amdgcn_fence(__ATOMIC_ACQUIRE, "agent");
            }
            __syncthreads();
        }
    }
}

// ---- A[b] = q[b] @ k[b]^T, f32, 64x64 tile / WG, 4x4 per thread ----
__global__ __launch_bounds__(256) void qk_gemm(
    const float* __restrict__ q, const float* __restrict__ k, float* __restrict__ A)
{
    __shared__ float qs[64][68];
    __shared__ float ks[64][68];
    int b = blockIdx.y;
    int t0 = (blockIdx.x >> 3) * 64;
    int s0 = (blockIdx.x & 7) * 64;
    const float* qb = q + (size_t)b * TT * TD;
    const float* kb = k + (size_t)b * TT * TD;
    int tid = threadIdx.x;
    int ty = tid >> 4, tx = tid & 15;
    float accr[4][4] = {};
    for (int k0 = 0; k0 < TD; k0 += 64) {
        for (int i = tid; i < 64 * 16; i += 256) {
            int r = i >> 4, c4 = i & 15;
            ((float4*)&qs[r][0])[c4] = ((const float4*)(qb + (size_t)(t0 + r) * TD + k0))[c4];
            ((float4*)&ks[r][0])[c4] = ((const float4*)(kb + (size_t)(s0 + r) * TD + k0))[c4];
        }
        __syncthreads();
#pragma unroll 4
        for (int kk = 0; kk < 64; kk += 4) {
            float4 qv[4], kv[4];
#pragma unroll
            for (int i = 0; i < 4; ++i) qv[i] = *(const float4*)&qs[ty * 4 + i][kk];
#pragma unroll
            for (int j = 0; j < 4; ++j) kv[j] = *(const float4*)&ks[tx * 4 + j][kk];
#pragma unroll
            for (int i = 0; i < 4; ++i)
#pragma unroll
                for (int j = 0; j < 4; ++j)
                    accr[i][j] += qv[i].x * kv[j].x + qv[i].y * kv[j].y
                                + qv[i].z * kv[j].z + qv[i].w * kv[j].w;
        }
        __syncthreads();
    }
    for (int i = 0; i < 4; ++i)
        for (int j = 0; j < 4; ++j)
            A[(size_t)b * TT * TT + (size_t)(t0 + ty * 4 + i) * TT + (s0 + tx * 4 + j)] = accr[i][j];
}

extern "C" void kernel_launch(void* const* d_in, const int* in_sizes, int n_in,
                              void* d_out, int out_size, void* d_ws, size_t ws_size,
                              hipStream_t stream)
{
    const int*   x      = (const int*)d_in[0];
    const float* embed  = (const float*)d_in[1];
    const float* Wih_q  = (const float*)d_in[2];
    const float* Whh_q  = (const float*)d_in[3];
    const float* bih_q  = (const float*)d_in[4];
    const float* bhh_q  = (const float*)d_in[5];
    const float* Wih_k  = (const float*)d_in[6];
    const float* Whh_k  = (const float*)d_in[7];
    const float* bih_k  = (const float*)d_in[8];
    const float* bhh_k  = (const float*)d_in[9];

    float* ws   = (float*)d_ws;
    float* q    = ws;                                   // 8388608 f
    float* kbuf = q + (size_t)TB * TT * TD;             // 8388608 f
    float* pre  = kbuf + (size_t)TB * TT * TD;          // 57344 f
    unsigned short* hbf = (unsigned short*)(pre + 2 * NTOK * 4 * TD);  // 65536 us
    int* flags = (int*)(hbf + 65536);                   // 128 int

    init_flags<<<1, 128, 0, stream>>>(flags);
    pre_tab_kernel<<<224, 256, 0, stream>>>(embed, Wih_q, bih_q, bhh_q,
                                            Wih_k, bih_k, bhh_k, pre);
    lstm_persist<<<128, 256, 0, stream>>>(Whh_q, Whh_k, pre, x, q, kbuf, hbf, flags);
    dim3 g(64, 32);
    qk_gemm<<<g, 256, 0, stream>>>(q, kbuf, (float*)d_out);
}

// Round 6
// 3027.518 us; speedup vs baseline: 1.3640x; 1.3640x over previous
//
#include <hip/hip_runtime.h>
#include <hip/hip_bf16.h>

// Encoder: e = embed[x]; q = LSTM_q(e); k = LSTM_k(e); A = q @ k^T (per batch)
// B=32, T=512, D=512, NUM_TOKENS=14.
//
// R6: fence-free persistent recurrence. R5's agent fences (wbL2/invL2 per WG
// per step) forced 133 MB of per-step L2 writebacks -> 7.9 us/step all-idle.
// Now: h crosses WGs via sc0 sc1 write-through stores / cache-bypass loads
// (per-access coherence, no cache-wide ops); flags via relaxed agent atomics;
// q/k f32 history stays lazily cached (flushed once at kernel end).

#define TB 32
#define TT 512
#define TD 512
#define NTOK 14

typedef __attribute__((ext_vector_type(8))) short short8;
typedef __attribute__((ext_vector_type(4))) float f32x4;

__device__ __forceinline__ float fsigmoid(float v) { return 1.f / (1.f + __expf(-v)); }
__device__ __forceinline__ float ftanh(float v) {
    float a = fabsf(v);
    float e = __expf(-2.f * a);
    float r = (1.f - e) / (1.f + e);
    return copysignf(r, v);
}
__device__ __forceinline__ unsigned short f2bf(float f) {
    __hip_bfloat16 h = __float2bfloat16(f);
    return __builtin_bit_cast(unsigned short, h);
}

// coherent (agent-visible) 16B load: bypasses L1/L2 -> never stale.
__device__ __forceinline__ short8 load16_coh(const unsigned short* p) {
    short8 r;
    asm volatile("global_load_dwordx4 %0, %1, off sc0 sc1" : "=v"(r) : "v"(p) : "memory");
    return r;
}
// coherent 2B store: write-through to coherent point (no dirty L2 line).
__device__ __forceinline__ void store2_coh(unsigned short* p, unsigned int v) {
    asm volatile("global_store_short %0, %1, off sc0 sc1" :: "v"(p), "v"(v) : "memory");
}

// ---- pre_tab[l][tok][2048] = embed[tok] @ W_ih_l^T + b_ih_l + b_hh_l ----
__global__ __launch_bounds__(256) void pre_tab_kernel(
    const float* __restrict__ embed,
    const float* __restrict__ Wih_q, const float* __restrict__ bih_q, const float* __restrict__ bhh_q,
    const float* __restrict__ Wih_k, const float* __restrict__ bih_k, const float* __restrict__ bhh_k,
    float* __restrict__ pre)
{
    int idx = blockIdx.x * 256 + threadIdx.x;   // 2*14*2048 = 57344 exactly
    int l = idx / (NTOK * 4 * TD);
    int r = idx % (NTOK * 4 * TD);
    int tok = r / (4 * TD), j = r % (4 * TD);
    const float* Wih = l ? Wih_k : Wih_q;
    float acc = l ? (bih_k[j] + bhh_k[j]) : (bih_q[j] + bhh_q[j]);
    const float4* e4 = (const float4*)(embed + (size_t)tok * TD);
    const float4* w4 = (const float4*)(Wih + (size_t)j * TD);
    for (int t2 = 0; t2 < TD / 4; ++t2) {
        float4 e = e4[t2], w = w4[t2];
        acc += e.x * w.x + e.y * w.y + e.z * w.z + e.w * w.w;
    }
    pre[idx] = acc;
}

__global__ void init_flags(int* flags) { flags[threadIdx.x] = 0; }

// ---- persistent LSTM: grid 128, wg>>6 = lstm l, (wg&63)*8 = dim chunk d0 ----
__global__ __launch_bounds__(256) void lstm_persist(
    const float* __restrict__ Whh_q, const float* __restrict__ Whh_k,
    const float* __restrict__ pre,
    const int* __restrict__ x,
    float* __restrict__ qout, float* __restrict__ kout,
    unsigned short* __restrict__ hbf,
    int* __restrict__ flags)
{
    __shared__ unsigned short w_lds[32][512];   // 32 KB, 16B-chunk XOR swizzled
    __shared__ unsigned char  x_lds[TB * TT];   // 16 KB
    __shared__ float          pre_lds[NTOK][32];// [tok][gate*8+dd]
    __shared__ float          g_lds[32][33];

    int wg  = blockIdx.x;
    int l   = wg >> 6;
    int wid = wg & 63;
    int d0  = wid << 3;
    int tid = threadIdx.x;
    int lane = tid & 63;
    int wv = tid >> 6;     // 4 waves
    int mt = wv & 1;       // batch tile
    int nt = wv >> 1;      // gate-row tile

    const float* Whh = l ? Whh_k : Whh_q;

    // stage W slice: LDS row r (=gate*8+dd) <- global row (r>>3)*TD + d0 + (r&7)
    // chunk = 8 bf16 (16 B); swizzle: store chunk c at position c ^ (r&7)
    {
        int r = tid >> 3;
        const float* src = Whh + (size_t)((r >> 3) * TD + d0 + (r & 7)) * TD;
        for (int i = 0; i < 8; ++i) {
            int c = (tid & 7) + 8 * i;
            float4 a = ((const float4*)src)[c * 2];
            float4 b = ((const float4*)src)[c * 2 + 1];
            unsigned short* dst = &w_lds[r][(c ^ (r & 7)) * 8];
            dst[0] = f2bf(a.x); dst[1] = f2bf(a.y); dst[2] = f2bf(a.z); dst[3] = f2bf(a.w);
            dst[4] = f2bf(b.x); dst[5] = f2bf(b.y); dst[6] = f2bf(b.z); dst[7] = f2bf(b.w);
        }
    }
    for (int i = tid; i < TB * TT; i += 256) x_lds[i] = (unsigned char)x[i];
    for (int i = tid; i < NTOK * 32; i += 256) {
        int tok = i >> 5, rr = i & 31;
        pre_lds[tok][rr] = pre[((size_t)l * NTOK + tok) * (4 * TD) + (rr >> 3) * TD + d0 + (rr & 7)];
    }
    __syncthreads();

    int b  = tid >> 3, dd = tid & 7;          // tail mapping
    float creg = 0.f;
    float* hist = l ? kout : qout;
    int* gflags = flags + l * 64;

    for (int t = 0; t < TT; ++t) {
        f32x4 acc = {0.f, 0.f, 0.f, 0.f};
        if (t > 0) {
            // A-frag: h[b][k]; lane: b = mt*16+(lane&15), k-offset (lane>>4)*8
            const unsigned short* hrow = hbf
                + (size_t)((((t - 1) & 1) * 2 + l) * TB + (mt * 16 + (lane & 15))) * TD
                + ((lane >> 4) * 8);
            short8 afr[16];
#pragma unroll
            for (int kk = 0; kk < 16; ++kk)
                afr[kk] = load16_coh(hrow + kk * 32);
            asm volatile("s_waitcnt vmcnt(0)" ::: "memory");
            __builtin_amdgcn_sched_barrier(0);
            int rr = nt * 16 + (lane & 15);   // LDS W row
#pragma unroll
            for (int kk = 0; kk < 16; ++kk) {
                int c = kk * 4 + (lane >> 4);
                short8 bfr = *(const short8*)&w_lds[rr][(c ^ (rr & 7)) * 8];
                acc = __builtin_amdgcn_mfma_f32_16x16x32_bf16(afr[kk], bfr, acc, 0, 0, 0);
            }
        }
        // C/D: col(lane&15)->gate-row, row((lane>>4)*4+reg)->batch
        {
            int gr = nt * 16 + (lane & 15);
            int gb = mt * 16 + ((lane >> 4) << 2);
#pragma unroll
            for (int r2 = 0; r2 < 4; ++r2) g_lds[gr][gb + r2] = acc[r2];
        }
        __syncthreads();

        // pointwise tail: thread <-> (b, dd)
        {
            int tok = x_lds[b * TT + t];
            float gi = g_lds[dd][b]      + pre_lds[tok][dd];
            float gf = g_lds[8 + dd][b]  + pre_lds[tok][8 + dd];
            float gg = g_lds[16 + dd][b] + pre_lds[tok][16 + dd];
            float go = g_lds[24 + dd][b] + pre_lds[tok][24 + dd];
            float i_ = fsigmoid(gi), f_ = fsigmoid(gf), g_ = ftanh(gg), o_ = fsigmoid(go);
            creg = f_ * creg + i_ * g_;
            float h = o_ * ftanh(creg);
            hist[((size_t)b * TT + t) * TD + d0 + dd] = h;   // plain (lazy L2)
            store2_coh(hbf + (size_t)(((t & 1) * 2 + l) * TB + b) * TD + d0 + dd,
                       (unsigned int)f2bf(h));
        }
        // drain own write-through stores, then WG-wide rendezvous:
        asm volatile("s_waitcnt vmcnt(0)" ::: "memory");
        __syncthreads();   // all 256 lanes' h-stores are at the coherent point

        if (t != TT - 1) {
            if (tid == 0)
                __hip_atomic_store(&gflags[wid], t + 1, __ATOMIC_RELAXED, __HIP_MEMORY_SCOPE_AGENT);
            if (tid < 64) {
                for (;;) {
                    int v = __hip_atomic_load(&gflags[tid], __ATOMIC_RELAXED, __HIP_MEMORY_SCOPE_AGENT);
                    if (__all(v >= t + 1)) break;
                    __builtin_amdgcn_s_sleep(1);
                }
            }
            __syncthreads();
        }
    }
}

// ---- A[b] = q[b] @ k[b]^T, f32, 64x64 tile / WG, 4x4 per thread ----
__global__ __launch_bounds__(256) void qk_gemm(
    const float* __restrict__ q, const float* __restrict__ k, float* __restrict__ A)
{
    __shared__ float qs[64][68];
    __shared__ float ks[64][68];
    int b = blockIdx.y;
    int t0 = (blockIdx.x >> 3) * 64;
    int s0 = (blockIdx.x & 7) * 64;
    const float* qb = q + (size_t)b * TT * TD;
    const float* kb = k + (size_t)b * TT * TD;
    int tid = threadIdx.x;
    int ty = tid >> 4, tx = tid & 15;
    float accr[4][4] = {};
    for (int k0 = 0; k0 < TD; k0 += 64) {
        for (int i = tid; i < 64 * 16; i += 256) {
            int r = i >> 4, c4 = i & 15;
            ((float4*)&qs[r][0])[c4] = ((const float4*)(qb + (size_t)(t0 + r) * TD + k0))[c4];
            ((float4*)&ks[r][0])[c4] = ((const float4*)(kb + (size_t)(s0 + r) * TD + k0))[c4];
        }
        __syncthreads();
#pragma unroll 4
        for (int kk = 0; kk < 64; kk += 4) {
            float4 qv[4], kv[4];
#pragma unroll
            for (int i = 0; i < 4; ++i) qv[i] = *(const float4*)&qs[ty * 4 + i][kk];
#pragma unroll
            for (int j = 0; j < 4; ++j) kv[j] = *(const float4*)&ks[tx * 4 + j][kk];
#pragma unroll
            for (int i = 0; i < 4; ++i)
#pragma unroll
                for (int j = 0; j < 4; ++j)
                    accr[i][j] += qv[i].x * kv[j].x + qv[i].y * kv[j].y
                                + qv[i].z * kv[j].z + qv[i].w * kv[j].w;
        }
        __syncthreads();
    }
    for (int i = 0; i < 4; ++i)
        for (int j = 0; j < 4; ++j)
            A[(size_t)b * TT * TT + (size_t)(t0 + ty * 4 + i) * TT + (s0 + tx * 4 + j)] = accr[i][j];
}

extern "C" void kernel_launch(void* const* d_in, const int* in_sizes, int n_in,
                              void* d_out, int out_size, void* d_ws, size_t ws_size,
                              hipStream_t stream)
{
    const int*   x      = (const int*)d_in[0];
    const float* embed  = (const float*)d_in[1];
    const float* Wih_q  = (const float*)d_in[2];
    const float* Whh_q  = (const float*)d_in[3];
    const float* bih_q  = (const float*)d_in[4];
    const float* bhh_q  = (const float*)d_in[5];
    const float* Wih_k  = (const float*)d_in[6];
    const float* Whh_k  = (const float*)d_in[7];
    const float* bih_k  = (const float*)d_in[8];
    const float* bhh_k  = (const float*)d_in[9];

    float* ws   = (float*)d_ws;
    float* q    = ws;                                   // 8388608 f
    float* kbuf = q + (size_t)TB * TT * TD;             // 8388608 f
    float* pre  = kbuf + (size_t)TB * TT * TD;          // 57344 f
    unsigned short* hbf = (unsigned short*)(pre + 2 * NTOK * 4 * TD);  // 65536 us
    int* flags = (int*)(hbf + 65536);                   // 128 int

    init_flags<<<1, 128, 0, stream>>>(flags);
    pre_tab_kernel<<<224, 256, 0, stream>>>(embed, Wih_q, bih_q, bhh_q,
                                            Wih_k, bih_k, bhh_k, pre);
    lstm_persist<<<128, 256, 0, stream>>>(Whh_q, Whh_k, pre, x, q, kbuf, hbf, flags);
    dim3 g(64, 32);
    qk_gemm<<<g, 256, 0, stream>>>(q, kbuf, (float*)d_out);
}